// Round 5
// baseline (2230.689 us; speedup 1.0000x reference)
//
#include <hip/hip_runtime.h>
#include <math.h>

// ---------------------------------------------------------------------------
// RecurrentNatureCNN: conv1(8x8,s4) -> conv2(4x4,s2) -> conv3(3x3,s1) -> FC
//                     -> LSTM(T=64,B=32,H=256)
// N = T*B = 2048 images.
// R4: LSTM weight stream is the bound (1 MB/step/CU through L1 = 6.8 us/step).
//     -> bf16 weights (512 KB), 32 k-quad slabs register-resident (128 VGPR),
//        7 slabs LDS-resident (56 KB), only 25 slabs (200 KB) streamed/step.
//     512 thr/block, thread j owns gate-cols j and j+512. h stays fp32.
// ---------------------------------------------------------------------------

#define NIMG 2048
#define REG_KQ 32
#define LDS_KQ 7
// streamed: kq in [REG_KQ+LDS_KQ, 64)

// ---- generic small transpose: in (R,C) -> out (C,R) -----------------------
__global__ void transpose_kernel(const float* __restrict__ in, float* __restrict__ out,
                                 int R, int C) {
    int idx = blockIdx.x * 256 + threadIdx.x;
    if (idx < R * C) {
        int r = idx / C, c = idx - r * C;
        out[c * R + r] = in[idx];
    }
}

// ---- pack whh (1024,256) fp32 -> bf16 quads: w4b[kq][j][4], kq=k/4 ---------
// thread j's quad kq = 8 bytes at ((kq*1024)+j)*4 ushorts (lane-coalesced).
__global__ void pack_whh_bf16_kernel(const float* __restrict__ whh,
                                     unsigned short* __restrict__ w4b) {
    int idx = blockIdx.x * 256 + threadIdx.x;  // 0..65535 = kq*1024 + j
    int kq = idx >> 10, j = idx & 1023;
    const float* src = whh + (size_t)j * 256 + kq * 4;
#pragma unroll
    for (int i = 0; i < 4; ++i) {
        unsigned u = __float_as_uint(src[i]);
        unsigned r = (u + 0x7fff + ((u >> 16) & 1)) >> 16;  // RNE to bf16
        w4b[idx * 4 + i] = (unsigned short)r;
    }
}

// ---- conv1: x (n,4,64,64)/255 -> relu -> (n,32,15,15) ----------------------
__global__ __launch_bounds__(1024) void conv1_kernel(const float* __restrict__ x,
                                                     const float* __restrict__ w,
                                                     const float* __restrict__ b,
                                                     float* __restrict__ out) {
    __shared__ float xs[4 * 64 * 64];  // 65536 B
    int n = blockIdx.x;
    int tid = threadIdx.x;
    const float* xp = x + (size_t)n * 16384;
    const float inv = 1.0f / 255.0f;
    for (int i = tid * 4; i < 16384; i += 4096) {
        float4 v = *(const float4*)(xp + i);
        xs[i + 0] = v.x * inv;
        xs[i + 1] = v.y * inv;
        xs[i + 2] = v.z * inv;
        xs[i + 3] = v.w * inv;
    }
    __syncthreads();
    int lane = tid & 63, wave = tid >> 6;
    int gg = __builtin_amdgcn_readfirstlane(wave & 3);  // oc group, wave-uniform
    int pos = (wave >> 2) * 64 + lane;                  // 0..255
    if (pos < 225) {
        int oy = pos / 15, ox = pos - oy * 15;
        float acc[8];
        const float* bp = b + gg * 8;
#pragma unroll
        for (int u = 0; u < 8; ++u) acc[u] = bp[u];
        for (int ic = 0; ic < 4; ++ic) {
#pragma unroll
            for (int ky = 0; ky < 8; ++ky) {
                const float* xrow = &xs[(ic * 64 + oy * 4 + ky) * 64 + ox * 4];
                float xr[8];
                *(float4*)&xr[0] = *(const float4*)&xrow[0];
                *(float4*)&xr[4] = *(const float4*)&xrow[4];
                const float* wrow = w + (gg * 8) * 256 + ic * 64 + ky * 8;
#pragma unroll
                for (int u = 0; u < 8; ++u) {
                    const float* wr = wrow + u * 256;
#pragma unroll
                    for (int kx = 0; kx < 8; ++kx) acc[u] += xr[kx] * wr[kx];
                }
            }
        }
        float* op = out + (size_t)n * 7200 + (gg * 8) * 225 + pos;
#pragma unroll
        for (int u = 0; u < 8; ++u) op[u * 225] = fmaxf(acc[u], 0.0f);
    }
}

// ---- conv2: z1 (n,32,15,15) -> relu -> (n,64,6,6) --------------------------
__global__ __launch_bounds__(768) void conv2_kernel(const float* __restrict__ x,
                                                    const float* __restrict__ wt,
                                                    const float* __restrict__ bias,
                                                    float* __restrict__ out) {
    __shared__ float xs[2][32 * 15 * 16];  // 61440 B
    int tid = threadIdx.x;
    int n0 = blockIdx.x * 2;
    for (int img = 0; img < 2; ++img) {
        const float* src = x + (size_t)(n0 + img) * 7200;
        for (int s = tid; s < 7200; s += 768) {
            int ic = s / 225;
            int rem = s - ic * 225;
            int r = rem / 15;
            int c = rem - r * 15;
            xs[img][(ic * 15 + r) * 16 + c] = src[s];
        }
    }
    __syncthreads();
    int lane = tid & 63, wave = tid >> 6;  // wave 0..11
    int img = wave / 6;
    int oy = wave - img * 6;
    int n = n0 + img;
    float bv = bias[lane];
    float* op = out + (size_t)n * 2304 + lane * 36;
    float acc[6];
#pragma unroll
    for (int u = 0; u < 6; ++u) acc[u] = bv;
    for (int ic = 0; ic < 32; ++ic) {
#pragma unroll
        for (int ky = 0; ky < 4; ++ky) {
            const float* xrow = &xs[img][(ic * 15 + oy * 2 + ky) * 16];
            float xr[16];
            *(float4*)&xr[0]  = *(const float4*)&xrow[0];
            *(float4*)&xr[4]  = *(const float4*)&xrow[4];
            *(float4*)&xr[8]  = *(const float4*)&xrow[8];
            *(float4*)&xr[12] = *(const float4*)&xrow[12];
            const float* wp = wt + ((ic * 4 + ky) * 4) * 64 + lane;
#pragma unroll
            for (int kx = 0; kx < 4; ++kx) {
                float wv = wp[kx * 64];
#pragma unroll
                for (int u = 0; u < 6; ++u) acc[u] += xr[u * 2 + kx] * wv;
            }
        }
    }
#pragma unroll
    for (int u = 0; u < 6; ++u) op[oy * 6 + u] = fmaxf(acc[u], 0.0f);
}

// ---- conv3: z2 (n,64,6,6) -> relu -> (n,64,4,4) ----------------------------
__global__ __launch_bounds__(512) void conv3_kernel(const float* __restrict__ x,
                                                    const float* __restrict__ wt,
                                                    const float* __restrict__ bias,
                                                    float* __restrict__ out) {
    __shared__ float xs[4][64 * 6 * 8];  // 49152 B
    int tid = threadIdx.x;
    int n0 = blockIdx.x * 4;
    for (int img = 0; img < 4; ++img) {
        const float* src = x + (size_t)(n0 + img) * 2304;
        for (int s = tid; s < 2304; s += 512) {
            int ic = s / 36;
            int rem = s - ic * 36;
            int r = rem / 6;
            int c = rem - r * 6;
            xs[img][(ic * 6 + r) * 8 + c] = src[s];
        }
    }
    __syncthreads();
    int lane = tid & 63, wave = tid >> 6;  // 0..7
    int img = wave >> 1;
    int half = wave & 1;
    int n = n0 + img;
    float bv = bias[lane];
    float* op = out + (size_t)n * 1024 + lane * 16;
    for (int q = 0; q < 2; ++q) {
        int oy = half * 2 + q;
        float acc[4];
#pragma unroll
        for (int u = 0; u < 4; ++u) acc[u] = bv;
        for (int ic = 0; ic < 64; ++ic) {
#pragma unroll
            for (int ky = 0; ky < 3; ++ky) {
                const float* xrow = &xs[img][(ic * 6 + oy + ky) * 8];
                float xr[8];
                *(float4*)&xr[0] = *(const float4*)&xrow[0];
                *(float4*)&xr[4] = *(const float4*)&xrow[4];
                const float* wp = wt + ((ic * 3 + ky) * 3) * 64 + lane;
#pragma unroll
                for (int kx = 0; kx < 3; ++kx) {
                    float wv = wp[kx * 64];
#pragma unroll
                    for (int u = 0; u < 4; ++u) acc[u] += xr[u + kx] * wv;
                }
            }
        }
#pragma unroll
        for (int u = 0; u < 4; ++u) op[oy * 4 + u] = fmaxf(acc[u], 0.0f);
    }
}

// ---- GEMM: C(M,N) = [relu]( A(M,K) @ B(N,K)^T + bias [+ bias2] ) -----------
__global__ __launch_bounds__(256) void gemm_bt(const float* __restrict__ A,
                                               const float* __restrict__ B,
                                               const float* __restrict__ bias,
                                               const float* __restrict__ bias2,
                                               float* __restrict__ C,
                                               int M, int N, int K, int relu) {
    __shared__ float As[16][68];
    __shared__ float Bs[16][68];
    int tid = threadIdx.x;
    int m0 = blockIdx.y * 64, n0 = blockIdx.x * 64;
    int tx = tid & 15, ty = tid >> 4;
    int lr = tid >> 2;
    int lk = (tid & 3) * 4;
    const float* Ap = A + (size_t)(m0 + lr) * K + lk;
    const float* Bp = B + (size_t)(n0 + lr) * K + lk;
    float acc[4][4];
#pragma unroll
    for (int i = 0; i < 4; ++i)
#pragma unroll
        for (int j = 0; j < 4; ++j) acc[i][j] = 0.0f;

    for (int k0 = 0; k0 < K; k0 += 16) {
        float4 av = *(const float4*)(Ap + k0);
        float4 bv = *(const float4*)(Bp + k0);
        __syncthreads();
        As[lk + 0][lr] = av.x;
        As[lk + 1][lr] = av.y;
        As[lk + 2][lr] = av.z;
        As[lk + 3][lr] = av.w;
        Bs[lk + 0][lr] = bv.x;
        Bs[lk + 1][lr] = bv.y;
        Bs[lk + 2][lr] = bv.z;
        Bs[lk + 3][lr] = bv.w;
        __syncthreads();
#pragma unroll
        for (int kk = 0; kk < 16; ++kk) {
            float a[4], b[4];
            *(float4*)a = *(const float4*)&As[kk][ty * 4];
            *(float4*)b = *(const float4*)&Bs[kk][tx * 4];
#pragma unroll
            for (int i = 0; i < 4; ++i)
#pragma unroll
                for (int j = 0; j < 4; ++j) acc[i][j] += a[i] * b[j];
        }
    }
    float bb[4];
#pragma unroll
    for (int j = 0; j < 4; ++j) {
        float v = bias[n0 + tx * 4 + j];
        if (bias2) v += bias2[n0 + tx * 4 + j];
        bb[j] = v;
    }
#pragma unroll
    for (int i = 0; i < 4; ++i) {
        float4 o;
        o.x = acc[i][0] + bb[0];
        o.y = acc[i][1] + bb[1];
        o.z = acc[i][2] + bb[2];
        o.w = acc[i][3] + bb[3];
        if (relu) {
            o.x = fmaxf(o.x, 0.0f);
            o.y = fmaxf(o.y, 0.0f);
            o.z = fmaxf(o.z, 0.0f);
            o.w = fmaxf(o.w, 0.0f);
        }
        *(float4*)&C[(size_t)(m0 + ty * 4 + i) * N + n0 + tx * 4] = o;
    }
}

// ---- bf16 pair unpack: dword = [lo bf16 | hi bf16] -> 2 fp32 ---------------
__device__ inline void bf16x2_unpack(unsigned d, float& lo, float& hi) {
    lo = __uint_as_float(d << 16);
    hi = __uint_as_float(d & 0xffff0000u);
}

// ---- LSTM: 32 blocks (one per env), 512 threads ----------------------------
// gi (2048,1024) = feats@w_ih^T + b_ih + b_hh (precomputed).
// Weights bf16, layout w4b[kq][j][4] (uint2 per (kq,col)). Thread j owns
// gate-cols j and j+512. Slabs 0..REG_KQ-1 live in VGPRs (loaded once),
// REG_KQ..REG_KQ+LDS_KQ-1 in LDS (loaded once), rest streamed from L2 each
// step (25 slabs = 200 KB). h stays fp32 in LDS (broadcast reads).
// Mask via linearity: (h*m)@W = m*(h@W).
__global__ __launch_bounds__(512, 2) void lstm_kernel(const float* __restrict__ gi,
                                                      const unsigned short* __restrict__ w4b,
                                                      const int* __restrict__ done,
                                                      const float* __restrict__ h0,
                                                      const float* __restrict__ c0,
                                                      float* __restrict__ out) {
    __shared__ float h[256];
    __shared__ float gates[1024];
    __shared__ uint2 wl[LDS_KQ * 1024];  // 57344 B
    int b = blockIdx.x, tid = threadIdx.x;
    const uint2* wq = (const uint2*)w4b;

    // register-resident slabs (cols tid, tid+512)
    uint2 wr0[REG_KQ], wr1[REG_KQ];
#pragma unroll
    for (int kq = 0; kq < REG_KQ; ++kq) {
        wr0[kq] = wq[kq * 1024 + tid];
        wr1[kq] = wq[kq * 1024 + tid + 512];
    }
    // LDS-resident slabs (contiguous region of wq)
    for (int i = tid; i < LDS_KQ * 1024; i += 512) wl[i] = wq[REG_KQ * 1024 + i];

    float c = 0.0f;
    if (tid < 256) {
        c = c0[b * 256 + tid];
        h[tid] = h0[b * 256 + tid];
    }
    __syncthreads();

    for (int t = 0; t < 64; ++t) {
        int row = t * 32 + b;
        float m = 1.0f - (float)done[row];
        float gv0 = gi[(size_t)row * 1024 + tid];
        float gv1 = gi[(size_t)row * 1024 + tid + 512];
        float4 a0 = {0.f, 0.f, 0.f, 0.f}, a1 = {0.f, 0.f, 0.f, 0.f};
        // register part
#pragma unroll
        for (int kq = 0; kq < REG_KQ; ++kq) {
            float4 hk = *(const float4*)&h[kq * 4];
            float l0, h0_, l1, h1_;
            bf16x2_unpack(wr0[kq].x, l0, h0_);
            bf16x2_unpack(wr0[kq].y, l1, h1_);
            a0.x += hk.x * l0;  a0.y += hk.y * h0_;
            a0.z += hk.z * l1;  a0.w += hk.w * h1_;
            bf16x2_unpack(wr1[kq].x, l0, h0_);
            bf16x2_unpack(wr1[kq].y, l1, h1_);
            a1.x += hk.x * l0;  a1.y += hk.y * h0_;
            a1.z += hk.z * l1;  a1.w += hk.w * h1_;
        }
        // LDS part
#pragma unroll
        for (int kq = REG_KQ; kq < REG_KQ + LDS_KQ; ++kq) {
            float4 hk = *(const float4*)&h[kq * 4];
            uint2 w0 = wl[(kq - REG_KQ) * 1024 + tid];
            uint2 w1 = wl[(kq - REG_KQ) * 1024 + tid + 512];
            float l0, h0_, l1, h1_;
            bf16x2_unpack(w0.x, l0, h0_);
            bf16x2_unpack(w0.y, l1, h1_);
            a0.x += hk.x * l0;  a0.y += hk.y * h0_;
            a0.z += hk.z * l1;  a0.w += hk.w * h1_;
            bf16x2_unpack(w1.x, l0, h0_);
            bf16x2_unpack(w1.y, l1, h1_);
            a1.x += hk.x * l0;  a1.y += hk.y * h0_;
            a1.z += hk.z * l1;  a1.w += hk.w * h1_;
        }
        // streamed part (L2-resident after step 0)
#pragma unroll
        for (int kq = REG_KQ + LDS_KQ; kq < 64; ++kq) {
            float4 hk = *(const float4*)&h[kq * 4];
            uint2 w0 = wq[kq * 1024 + tid];
            uint2 w1 = wq[kq * 1024 + tid + 512];
            float l0, h0_, l1, h1_;
            bf16x2_unpack(w0.x, l0, h0_);
            bf16x2_unpack(w0.y, l1, h1_);
            a0.x += hk.x * l0;  a0.y += hk.y * h0_;
            a0.z += hk.z * l1;  a0.w += hk.w * h1_;
            bf16x2_unpack(w1.x, l0, h0_);
            bf16x2_unpack(w1.y, l1, h1_);
            a1.x += hk.x * l0;  a1.y += hk.y * h0_;
            a1.z += hk.z * l1;  a1.w += hk.w * h1_;
        }
        float s0 = (a0.x + a0.y) + (a0.z + a0.w);
        float s1 = (a1.x + a1.y) + (a1.z + a1.w);
        gates[tid] = gv0 + m * s0;
        gates[tid + 512] = gv1 + m * s1;
        __syncthreads();
        if (tid < 256) {
            float g_i = gates[tid];
            float g_f = gates[256 + tid];
            float g_g = gates[512 + tid];
            float g_o = gates[768 + tid];
            float si = 1.0f / (1.0f + __expf(-g_i));
            float sf = 1.0f / (1.0f + __expf(-g_f));
            float so = 1.0f / (1.0f + __expf(-g_o));
            float tg = tanhf(g_g);
            c = sf * (c * m) + si * tg;
            float hn = so * tanhf(c);
            h[tid] = hn;
            out[(size_t)row * 256 + tid] = hn;
        }
        __syncthreads();
    }
}

// ---------------------------------------------------------------------------
extern "C" void kernel_launch(void* const* d_in, const int* in_sizes, int n_in,
                              void* d_out, int out_size, void* d_ws, size_t ws_size,
                              hipStream_t stream) {
    const float* x    = (const float*)d_in[0];
    const int*   done = (const int*)d_in[1];
    const float* w1   = (const float*)d_in[2];
    const float* b1   = (const float*)d_in[3];
    const float* w2   = (const float*)d_in[4];
    const float* b2   = (const float*)d_in[5];
    const float* w3   = (const float*)d_in[6];
    const float* b3   = (const float*)d_in[7];
    const float* fcw  = (const float*)d_in[8];
    const float* fcb  = (const float*)d_in[9];
    const float* wih  = (const float*)d_in[10];
    const float* whh  = (const float*)d_in[11];
    const float* bih  = (const float*)d_in[12];
    const float* bhh  = (const float*)d_in[13];
    const float* h0   = (const float*)d_in[14];
    const float* c0   = (const float*)d_in[15];
    float* out = (float*)d_out;
    float* ws = (float*)d_ws;

    // workspace layout (floats). z3/feats/gi reuse z1's region (z1 dead then).
    float* z1    = ws + 0;          // 14,745,600
    float* z2    = ws + 14745600;   //  4,718,592 (ends 19,464,192)
    float* z3    = ws + 0;          //  2,097,152
    float* feats = ws + 2097152;    //  1,048,576
    float* gi    = ws + 3145728;    //  2,097,152 (ends 5,242,880)
    float* w2t   = ws + 19464192;   //     32,768
    float* w3t   = ws + 19496960;   //     36,864
    unsigned short* w4b = (unsigned short*)(ws + 19533824);  // 512 KB (131072 floats)

    transpose_kernel<<<(64 * 512 + 255) / 256, 256, 0, stream>>>(w2, w2t, 64, 512);
    transpose_kernel<<<(64 * 576 + 255) / 256, 256, 0, stream>>>(w3, w3t, 64, 576);
    pack_whh_bf16_kernel<<<256, 256, 0, stream>>>(whh, w4b);

    conv1_kernel<<<NIMG, 1024, 0, stream>>>(x, w1, b1, z1);
    conv2_kernel<<<NIMG / 2, 768, 0, stream>>>(z1, w2t, b2, z2);
    conv3_kernel<<<NIMG / 4, 512, 0, stream>>>(z2, w3t, b3, z3);

    gemm_bt<<<dim3(512 / 64, NIMG / 64), 256, 0, stream>>>(z3, fcw, fcb, nullptr, feats,
                                                           NIMG, 512, 1024, 1);
    gemm_bt<<<dim3(1024 / 64, NIMG / 64), 256, 0, stream>>>(feats, wih, bih, bhh, gi,
                                                            NIMG, 1024, 512, 0);

    lstm_kernel<<<32, 512, 0, stream>>>(gi, w4b, done, h0, c0, out);
}

// Round 6
// 1185.712 us; speedup vs baseline: 1.8813x; 1.8813x over previous
//
#include <hip/hip_runtime.h>
#include <math.h>

// ---------------------------------------------------------------------------
// RecurrentNatureCNN: conv1(8x8,s4) -> conv2(4x4,s2) -> conv3(3x3,s1) -> FC
//                     -> LSTM(T=64,B=32,H=256)
// N = T*B = 2048 images.
// R5: LSTM = R3 structure (32 blk x 1024 thr, 1 gate-col/thread) + bf16
//     weights (512 KB/step/CU stream vs 1 MB fp32). R4's VGPR-resident slabs
//     SPILLED to scratch (WRITE_SIZE 2->16.7 MB) — reverted. Fast tanh in
//     epilogue. Convs/GEMMs unchanged (awaiting clean profile).
// ---------------------------------------------------------------------------

#define NIMG 2048

// ---- generic small transpose: in (R,C) -> out (C,R) -----------------------
__global__ void transpose_kernel(const float* __restrict__ in, float* __restrict__ out,
                                 int R, int C) {
    int idx = blockIdx.x * 256 + threadIdx.x;
    if (idx < R * C) {
        int r = idx / C, c = idx - r * C;
        out[c * R + r] = in[idx];
    }
}

// ---- pack whh (1024,256) fp32 -> bf16 quads: w4b[kq][j][4], kq=k/4 ---------
// thread j's quad kq = 8 bytes (uint2) at (kq*1024+j) — lane-coalesced.
// dword0 = bf(k0) | bf(k1)<<16 ; dword1 = bf(k2) | bf(k3)<<16.
__global__ void pack_whh_bf16_kernel(const float* __restrict__ whh,
                                     unsigned short* __restrict__ w4b) {
    int idx = blockIdx.x * 256 + threadIdx.x;  // 0..65535 = kq*1024 + j
    int kq = idx >> 10, j = idx & 1023;
    const float* src = whh + (size_t)j * 256 + kq * 4;
#pragma unroll
    for (int i = 0; i < 4; ++i) {
        unsigned u = __float_as_uint(src[i]);
        unsigned r = (u + 0x7fff + ((u >> 16) & 1)) >> 16;  // RNE to bf16
        w4b[idx * 4 + i] = (unsigned short)r;
    }
}

// ---- conv1: x (n,4,64,64)/255 -> relu -> (n,32,15,15) ----------------------
__global__ __launch_bounds__(1024) void conv1_kernel(const float* __restrict__ x,
                                                     const float* __restrict__ w,
                                                     const float* __restrict__ b,
                                                     float* __restrict__ out) {
    __shared__ float xs[4 * 64 * 64];  // 65536 B
    int n = blockIdx.x;
    int tid = threadIdx.x;
    const float* xp = x + (size_t)n * 16384;
    const float inv = 1.0f / 255.0f;
    for (int i = tid * 4; i < 16384; i += 4096) {
        float4 v = *(const float4*)(xp + i);
        xs[i + 0] = v.x * inv;
        xs[i + 1] = v.y * inv;
        xs[i + 2] = v.z * inv;
        xs[i + 3] = v.w * inv;
    }
    __syncthreads();
    int lane = tid & 63, wave = tid >> 6;
    int gg = __builtin_amdgcn_readfirstlane(wave & 3);  // oc group, wave-uniform
    int pos = (wave >> 2) * 64 + lane;                  // 0..255
    if (pos < 225) {
        int oy = pos / 15, ox = pos - oy * 15;
        float acc[8];
        const float* bp = b + gg * 8;
#pragma unroll
        for (int u = 0; u < 8; ++u) acc[u] = bp[u];
        for (int ic = 0; ic < 4; ++ic) {
#pragma unroll
            for (int ky = 0; ky < 8; ++ky) {
                const float* xrow = &xs[(ic * 64 + oy * 4 + ky) * 64 + ox * 4];
                float xr[8];
                *(float4*)&xr[0] = *(const float4*)&xrow[0];
                *(float4*)&xr[4] = *(const float4*)&xrow[4];
                const float* wrow = w + (gg * 8) * 256 + ic * 64 + ky * 8;
#pragma unroll
                for (int u = 0; u < 8; ++u) {
                    const float* wr = wrow + u * 256;
#pragma unroll
                    for (int kx = 0; kx < 8; ++kx) acc[u] += xr[kx] * wr[kx];
                }
            }
        }
        float* op = out + (size_t)n * 7200 + (gg * 8) * 225 + pos;
#pragma unroll
        for (int u = 0; u < 8; ++u) op[u * 225] = fmaxf(acc[u], 0.0f);
    }
}

// ---- conv2: z1 (n,32,15,15) -> relu -> (n,64,6,6) --------------------------
__global__ __launch_bounds__(768) void conv2_kernel(const float* __restrict__ x,
                                                    const float* __restrict__ wt,
                                                    const float* __restrict__ bias,
                                                    float* __restrict__ out) {
    __shared__ float xs[2][32 * 15 * 16];  // 61440 B
    int tid = threadIdx.x;
    int n0 = blockIdx.x * 2;
    for (int img = 0; img < 2; ++img) {
        const float* src = x + (size_t)(n0 + img) * 7200;
        for (int s = tid; s < 7200; s += 768) {
            int ic = s / 225;
            int rem = s - ic * 225;
            int r = rem / 15;
            int c = rem - r * 15;
            xs[img][(ic * 15 + r) * 16 + c] = src[s];
        }
    }
    __syncthreads();
    int lane = tid & 63, wave = tid >> 6;  // wave 0..11
    int img = wave / 6;
    int oy = wave - img * 6;
    int n = n0 + img;
    float bv = bias[lane];
    float* op = out + (size_t)n * 2304 + lane * 36;
    float acc[6];
#pragma unroll
    for (int u = 0; u < 6; ++u) acc[u] = bv;
    for (int ic = 0; ic < 32; ++ic) {
#pragma unroll
        for (int ky = 0; ky < 4; ++ky) {
            const float* xrow = &xs[img][(ic * 15 + oy * 2 + ky) * 16];
            float xr[16];
            *(float4*)&xr[0]  = *(const float4*)&xrow[0];
            *(float4*)&xr[4]  = *(const float4*)&xrow[4];
            *(float4*)&xr[8]  = *(const float4*)&xrow[8];
            *(float4*)&xr[12] = *(const float4*)&xrow[12];
            const float* wp = wt + ((ic * 4 + ky) * 4) * 64 + lane;
#pragma unroll
            for (int kx = 0; kx < 4; ++kx) {
                float wv = wp[kx * 64];
#pragma unroll
                for (int u = 0; u < 6; ++u) acc[u] += xr[u * 2 + kx] * wv;
            }
        }
    }
#pragma unroll
    for (int u = 0; u < 6; ++u) op[oy * 6 + u] = fmaxf(acc[u], 0.0f);
}

// ---- conv3: z2 (n,64,6,6) -> relu -> (n,64,4,4) ----------------------------
__global__ __launch_bounds__(512) void conv3_kernel(const float* __restrict__ x,
                                                    const float* __restrict__ wt,
                                                    const float* __restrict__ bias,
                                                    float* __restrict__ out) {
    __shared__ float xs[4][64 * 6 * 8];  // 49152 B
    int tid = threadIdx.x;
    int n0 = blockIdx.x * 4;
    for (int img = 0; img < 4; ++img) {
        const float* src = x + (size_t)(n0 + img) * 2304;
        for (int s = tid; s < 2304; s += 512) {
            int ic = s / 36;
            int rem = s - ic * 36;
            int r = rem / 6;
            int c = rem - r * 6;
            xs[img][(ic * 6 + r) * 8 + c] = src[s];
        }
    }
    __syncthreads();
    int lane = tid & 63, wave = tid >> 6;  // 0..7
    int img = wave >> 1;
    int half = wave & 1;
    int n = n0 + img;
    float bv = bias[lane];
    float* op = out + (size_t)n * 1024 + lane * 16;
    for (int q = 0; q < 2; ++q) {
        int oy = half * 2 + q;
        float acc[4];
#pragma unroll
        for (int u = 0; u < 4; ++u) acc[u] = bv;
        for (int ic = 0; ic < 64; ++ic) {
#pragma unroll
            for (int ky = 0; ky < 3; ++ky) {
                const float* xrow = &xs[img][(ic * 6 + oy + ky) * 8];
                float xr[8];
                *(float4*)&xr[0] = *(const float4*)&xrow[0];
                *(float4*)&xr[4] = *(const float4*)&xrow[4];
                const float* wp = wt + ((ic * 3 + ky) * 3) * 64 + lane;
#pragma unroll
                for (int kx = 0; kx < 3; ++kx) {
                    float wv = wp[kx * 64];
#pragma unroll
                    for (int u = 0; u < 4; ++u) acc[u] += xr[u + kx] * wv;
                }
            }
        }
#pragma unroll
        for (int u = 0; u < 4; ++u) op[oy * 4 + u] = fmaxf(acc[u], 0.0f);
    }
}

// ---- GEMM: C(M,N) = [relu]( A(M,K) @ B(N,K)^T + bias [+ bias2] ) -----------
__global__ __launch_bounds__(256) void gemm_bt(const float* __restrict__ A,
                                               const float* __restrict__ B,
                                               const float* __restrict__ bias,
                                               const float* __restrict__ bias2,
                                               float* __restrict__ C,
                                               int M, int N, int K, int relu) {
    __shared__ float As[16][68];
    __shared__ float Bs[16][68];
    int tid = threadIdx.x;
    int m0 = blockIdx.y * 64, n0 = blockIdx.x * 64;
    int tx = tid & 15, ty = tid >> 4;
    int lr = tid >> 2;
    int lk = (tid & 3) * 4;
    const float* Ap = A + (size_t)(m0 + lr) * K + lk;
    const float* Bp = B + (size_t)(n0 + lr) * K + lk;
    float acc[4][4];
#pragma unroll
    for (int i = 0; i < 4; ++i)
#pragma unroll
        for (int j = 0; j < 4; ++j) acc[i][j] = 0.0f;

    for (int k0 = 0; k0 < K; k0 += 16) {
        float4 av = *(const float4*)(Ap + k0);
        float4 bv = *(const float4*)(Bp + k0);
        __syncthreads();
        As[lk + 0][lr] = av.x;
        As[lk + 1][lr] = av.y;
        As[lk + 2][lr] = av.z;
        As[lk + 3][lr] = av.w;
        Bs[lk + 0][lr] = bv.x;
        Bs[lk + 1][lr] = bv.y;
        Bs[lk + 2][lr] = bv.z;
        Bs[lk + 3][lr] = bv.w;
        __syncthreads();
#pragma unroll
        for (int kk = 0; kk < 16; ++kk) {
            float a[4], b[4];
            *(float4*)a = *(const float4*)&As[kk][ty * 4];
            *(float4*)b = *(const float4*)&Bs[kk][tx * 4];
#pragma unroll
            for (int i = 0; i < 4; ++i)
#pragma unroll
                for (int j = 0; j < 4; ++j) acc[i][j] += a[i] * b[j];
        }
    }
    float bb[4];
#pragma unroll
    for (int j = 0; j < 4; ++j) {
        float v = bias[n0 + tx * 4 + j];
        if (bias2) v += bias2[n0 + tx * 4 + j];
        bb[j] = v;
    }
#pragma unroll
    for (int i = 0; i < 4; ++i) {
        float4 o;
        o.x = acc[i][0] + bb[0];
        o.y = acc[i][1] + bb[1];
        o.z = acc[i][2] + bb[2];
        o.w = acc[i][3] + bb[3];
        if (relu) {
            o.x = fmaxf(o.x, 0.0f);
            o.y = fmaxf(o.y, 0.0f);
            o.z = fmaxf(o.z, 0.0f);
            o.w = fmaxf(o.w, 0.0f);
        }
        *(float4*)&C[(size_t)(m0 + ty * 4 + i) * N + n0 + tx * 4] = o;
    }
}

// ---- bf16 pair unpack: dword = [lo bf16 | hi bf16] -> 2 fp32 ---------------
__device__ inline void bf16x2_unpack(unsigned d, float& lo, float& hi) {
    lo = __uint_as_float(d << 16);
    hi = __uint_as_float(d & 0xffff0000u);
}

__device__ inline float fast_tanh(float x) {
    // tanh(x) = 1 - 2/(exp(2x)+1)
    return 1.0f - 2.0f / (__expf(2.0f * x) + 1.0f);
}

// ---- LSTM: 32 blocks (one per env), 1024 threads ---------------------------
// gi (2048,1024) = feats@w_ih^T + b_ih + b_hh (precomputed). w4b = bf16-packed
// whh: thread j's K-quad kq is the uint2 at (kq*1024 + j) -> coalesced 8 B
// loads, 64/thread/step = 512 KB/step/CU streamed from L2 (the bound:
// ~3.3 us/step at 64 B/clk L1 refill). h stays fp32 in LDS (broadcast reads
// are conflict-free). Mask via linearity: (h*m)@W = m*(h@W).
__global__ __launch_bounds__(1024) void lstm_kernel(const float* __restrict__ gi,
                                                    const unsigned short* __restrict__ w4b,
                                                    const int* __restrict__ done,
                                                    const float* __restrict__ h0,
                                                    const float* __restrict__ c0,
                                                    float* __restrict__ out) {
    __shared__ float h[256];
    __shared__ float gates[1024];
    int b = blockIdx.x, tid = threadIdx.x;
    float c = 0.0f;
    if (tid < 256) {
        c = c0[b * 256 + tid];
        h[tid] = h0[b * 256 + tid];
    }
    __syncthreads();
    const uint2* wq = (const uint2*)w4b + tid;  // + kq*1024
    for (int t = 0; t < 64; ++t) {
        int row = t * 32 + b;
        float m = 1.0f - (float)done[row];
        float gv = gi[(size_t)row * 1024 + tid];
        float4 a = {0.f, 0.f, 0.f, 0.f};
#pragma unroll 8
        for (int kq = 0; kq < 64; ++kq) {
            float4 hk = *(const float4*)&h[kq * 4];
            uint2 w = wq[(size_t)kq * 1024];
            float l0, h0_, l1, h1_;
            bf16x2_unpack(w.x, l0, h0_);
            bf16x2_unpack(w.y, l1, h1_);
            a.x += hk.x * l0;
            a.y += hk.y * h0_;
            a.z += hk.z * l1;
            a.w += hk.w * h1_;
        }
        float s = (a.x + a.y) + (a.z + a.w);
        gates[tid] = gv + m * s;
        __syncthreads();
        if (tid < 256) {
            float g_i = gates[tid];
            float g_f = gates[256 + tid];
            float g_g = gates[512 + tid];
            float g_o = gates[768 + tid];
            float si = 1.0f / (1.0f + __expf(-g_i));
            float sf = 1.0f / (1.0f + __expf(-g_f));
            float so = 1.0f / (1.0f + __expf(-g_o));
            float tg = fast_tanh(g_g);
            c = sf * (c * m) + si * tg;
            float hn = so * fast_tanh(c);
            h[tid] = hn;
            out[(size_t)row * 256 + tid] = hn;
        }
        __syncthreads();
    }
}

// ---------------------------------------------------------------------------
extern "C" void kernel_launch(void* const* d_in, const int* in_sizes, int n_in,
                              void* d_out, int out_size, void* d_ws, size_t ws_size,
                              hipStream_t stream) {
    const float* x    = (const float*)d_in[0];
    const int*   done = (const int*)d_in[1];
    const float* w1   = (const float*)d_in[2];
    const float* b1   = (const float*)d_in[3];
    const float* w2   = (const float*)d_in[4];
    const float* b2   = (const float*)d_in[5];
    const float* w3   = (const float*)d_in[6];
    const float* b3   = (const float*)d_in[7];
    const float* fcw  = (const float*)d_in[8];
    const float* fcb  = (const float*)d_in[9];
    const float* wih  = (const float*)d_in[10];
    const float* whh  = (const float*)d_in[11];
    const float* bih  = (const float*)d_in[12];
    const float* bhh  = (const float*)d_in[13];
    const float* h0   = (const float*)d_in[14];
    const float* c0   = (const float*)d_in[15];
    float* out = (float*)d_out;
    float* ws = (float*)d_ws;

    // workspace layout (floats). z3/feats/gi reuse z1's region (z1 dead then).
    float* z1    = ws + 0;          // 14,745,600
    float* z2    = ws + 14745600;   //  4,718,592 (ends 19,464,192)
    float* z3    = ws + 0;          //  2,097,152
    float* feats = ws + 2097152;    //  1,048,576
    float* gi    = ws + 3145728;    //  2,097,152 (ends 5,242,880)
    float* w2t   = ws + 19464192;   //     32,768
    float* w3t   = ws + 19496960;   //     36,864
    unsigned short* w4b = (unsigned short*)(ws + 19533824);  // 512 KB

    transpose_kernel<<<(64 * 512 + 255) / 256, 256, 0, stream>>>(w2, w2t, 64, 512);
    transpose_kernel<<<(64 * 576 + 255) / 256, 256, 0, stream>>>(w3, w3t, 64, 576);
    pack_whh_bf16_kernel<<<256, 256, 0, stream>>>(whh, w4b);

    conv1_kernel<<<NIMG, 1024, 0, stream>>>(x, w1, b1, z1);
    conv2_kernel<<<NIMG / 2, 768, 0, stream>>>(z1, w2t, b2, z2);
    conv3_kernel<<<NIMG / 4, 512, 0, stream>>>(z2, w3t, b3, z3);

    gemm_bt<<<dim3(512 / 64, NIMG / 64), 256, 0, stream>>>(z3, fcw, fcb, nullptr, feats,
                                                           NIMG, 512, 1024, 1);
    gemm_bt<<<dim3(1024 / 64, NIMG / 64), 256, 0, stream>>>(feats, wih, bih, bhh, gi,
                                                            NIMG, 1024, 512, 0);

    lstm_kernel<<<32, 1024, 0, stream>>>(gi, w4b, done, h0, c0, out);
}

// Round 7
// 953.735 us; speedup vs baseline: 2.3389x; 1.2432x over previous
//
#include <hip/hip_runtime.h>
#include <math.h>

// ---------------------------------------------------------------------------
// RecurrentNatureCNN: conv1(8x8,s4) -> conv2(4x4,s2) -> conv3(3x3,s1) -> FC
//                     -> LSTM(T=64,B=32,H=256)
// N = T*B = 2048 images.
// R6: LSTM inner product -> v_dot2_f32_f16 (f16 weights + f16x2 h in LDS,
//     fp32 accum). R5 proved the bound is VALU instrs on 32 CUs, not bytes:
//     bf16 halved the stream with zero speedup. dot2 cuts ~40 instr/32 MACs
//     to ~13. Weight layout [kg][col][16] keeps loads coalesced and address
//     adds amortized (2 dwordx4 per 32 B chunk).
// ---------------------------------------------------------------------------

#define NIMG 2048

typedef _Float16 half2_t __attribute__((ext_vector_type(2)));

__device__ inline unsigned short f2h_bits(float f) {
    union { _Float16 h; unsigned short u; } x;
    x.h = (_Float16)f;
    return x.u;
}

__device__ inline float dot2(unsigned hu, unsigned wu, float acc) {
    union { unsigned u; half2_t h; } a, b;
    a.u = hu; b.u = wu;
#if __has_builtin(__builtin_amdgcn_fdot2)
    return __builtin_amdgcn_fdot2(a.h, b.h, acc, false);
#else
    return acc + (float)a.h.x * (float)b.h.x + (float)a.h.y * (float)b.h.y;
#endif
}

// ---- generic small transpose: in (R,C) -> out (C,R) -----------------------
__global__ void transpose_kernel(const float* __restrict__ in, float* __restrict__ out,
                                 int R, int C) {
    int idx = blockIdx.x * 256 + threadIdx.x;
    if (idx < R * C) {
        int r = idx / C, c = idx - r * C;
        out[c * R + r] = in[idx];
    }
}

// ---- pack whh (1024,256) fp32 -> f16: w6[kg][j][16], kg=k/16 ---------------
// thread per (kg,j): 16 consecutive k-values of gate-col j -> 32 B.
__global__ void pack_whh_f16_kernel(const float* __restrict__ whh,
                                    unsigned short* __restrict__ w6) {
    int idx = blockIdx.x * 256 + threadIdx.x;  // 0..16383 = kg*1024 + j
    int kg = idx >> 10, j = idx & 1023;
    const float* src = whh + (size_t)j * 256 + kg * 16;
    unsigned short* dst = w6 + (size_t)idx * 16;
#pragma unroll
    for (int i = 0; i < 16; ++i) dst[i] = f2h_bits(src[i]);
}

// ---- conv1: x (n,4,64,64)/255 -> relu -> (n,32,15,15) ----------------------
__global__ __launch_bounds__(1024) void conv1_kernel(const float* __restrict__ x,
                                                     const float* __restrict__ w,
                                                     const float* __restrict__ b,
                                                     float* __restrict__ out) {
    __shared__ float xs[4 * 64 * 64];  // 65536 B
    int n = blockIdx.x;
    int tid = threadIdx.x;
    const float* xp = x + (size_t)n * 16384;
    const float inv = 1.0f / 255.0f;
    for (int i = tid * 4; i < 16384; i += 4096) {
        float4 v = *(const float4*)(xp + i);
        xs[i + 0] = v.x * inv;
        xs[i + 1] = v.y * inv;
        xs[i + 2] = v.z * inv;
        xs[i + 3] = v.w * inv;
    }
    __syncthreads();
    int lane = tid & 63, wave = tid >> 6;
    int gg = __builtin_amdgcn_readfirstlane(wave & 3);  // oc group, wave-uniform
    int pos = (wave >> 2) * 64 + lane;                  // 0..255
    if (pos < 225) {
        int oy = pos / 15, ox = pos - oy * 15;
        float acc[8];
        const float* bp = b + gg * 8;
#pragma unroll
        for (int u = 0; u < 8; ++u) acc[u] = bp[u];
        for (int ic = 0; ic < 4; ++ic) {
#pragma unroll
            for (int ky = 0; ky < 8; ++ky) {
                const float* xrow = &xs[(ic * 64 + oy * 4 + ky) * 64 + ox * 4];
                float xr[8];
                *(float4*)&xr[0] = *(const float4*)&xrow[0];
                *(float4*)&xr[4] = *(const float4*)&xrow[4];
                const float* wrow = w + (gg * 8) * 256 + ic * 64 + ky * 8;
#pragma unroll
                for (int u = 0; u < 8; ++u) {
                    const float* wr = wrow + u * 256;
#pragma unroll
                    for (int kx = 0; kx < 8; ++kx) acc[u] += xr[kx] * wr[kx];
                }
            }
        }
        float* op = out + (size_t)n * 7200 + (gg * 8) * 225 + pos;
#pragma unroll
        for (int u = 0; u < 8; ++u) op[u * 225] = fmaxf(acc[u], 0.0f);
    }
}

// ---- conv2: z1 (n,32,15,15) -> relu -> (n,64,6,6) --------------------------
__global__ __launch_bounds__(768) void conv2_kernel(const float* __restrict__ x,
                                                    const float* __restrict__ wt,
                                                    const float* __restrict__ bias,
                                                    float* __restrict__ out) {
    __shared__ float xs[2][32 * 15 * 16];  // 61440 B
    int tid = threadIdx.x;
    int n0 = blockIdx.x * 2;
    for (int img = 0; img < 2; ++img) {
        const float* src = x + (size_t)(n0 + img) * 7200;
        for (int s = tid; s < 7200; s += 768) {
            int ic = s / 225;
            int rem = s - ic * 225;
            int r = rem / 15;
            int c = rem - r * 15;
            xs[img][(ic * 15 + r) * 16 + c] = src[s];
        }
    }
    __syncthreads();
    int lane = tid & 63, wave = tid >> 6;  // wave 0..11
    int img = wave / 6;
    int oy = wave - img * 6;
    int n = n0 + img;
    float bv = bias[lane];
    float* op = out + (size_t)n * 2304 + lane * 36;
    float acc[6];
#pragma unroll
    for (int u = 0; u < 6; ++u) acc[u] = bv;
    for (int ic = 0; ic < 32; ++ic) {
#pragma unroll
        for (int ky = 0; ky < 4; ++ky) {
            const float* xrow = &xs[img][(ic * 15 + oy * 2 + ky) * 16];
            float xr[16];
            *(float4*)&xr[0]  = *(const float4*)&xrow[0];
            *(float4*)&xr[4]  = *(const float4*)&xrow[4];
            *(float4*)&xr[8]  = *(const float4*)&xrow[8];
            *(float4*)&xr[12] = *(const float4*)&xrow[12];
            const float* wp = wt + ((ic * 4 + ky) * 4) * 64 + lane;
#pragma unroll
            for (int kx = 0; kx < 4; ++kx) {
                float wv = wp[kx * 64];
#pragma unroll
                for (int u = 0; u < 6; ++u) acc[u] += xr[u * 2 + kx] * wv;
            }
        }
    }
#pragma unroll
    for (int u = 0; u < 6; ++u) op[oy * 6 + u] = fmaxf(acc[u], 0.0f);
}

// ---- conv3: z2 (n,64,6,6) -> relu -> (n,64,4,4) ----------------------------
__global__ __launch_bounds__(512) void conv3_kernel(const float* __restrict__ x,
                                                    const float* __restrict__ wt,
                                                    const float* __restrict__ bias,
                                                    float* __restrict__ out) {
    __shared__ float xs[4][64 * 6 * 8];  // 49152 B
    int tid = threadIdx.x;
    int n0 = blockIdx.x * 4;
    for (int img = 0; img < 4; ++img) {
        const float* src = x + (size_t)(n0 + img) * 2304;
        for (int s = tid; s < 2304; s += 512) {
            int ic = s / 36;
            int rem = s - ic * 36;
            int r = rem / 6;
            int c = rem - r * 6;
            xs[img][(ic * 6 + r) * 8 + c] = src[s];
        }
    }
    __syncthreads();
    int lane = tid & 63, wave = tid >> 6;  // 0..7
    int img = wave >> 1;
    int half = wave & 1;
    int n = n0 + img;
    float bv = bias[lane];
    float* op = out + (size_t)n * 1024 + lane * 16;
    for (int q = 0; q < 2; ++q) {
        int oy = half * 2 + q;
        float acc[4];
#pragma unroll
        for (int u = 0; u < 4; ++u) acc[u] = bv;
        for (int ic = 0; ic < 64; ++ic) {
#pragma unroll
            for (int ky = 0; ky < 3; ++ky) {
                const float* xrow = &xs[img][(ic * 6 + oy + ky) * 8];
                float xr[8];
                *(float4*)&xr[0] = *(const float4*)&xrow[0];
                *(float4*)&xr[4] = *(const float4*)&xrow[4];
                const float* wp = wt + ((ic * 3 + ky) * 3) * 64 + lane;
#pragma unroll
                for (int kx = 0; kx < 3; ++kx) {
                    float wv = wp[kx * 64];
#pragma unroll
                    for (int u = 0; u < 4; ++u) acc[u] += xr[u + kx] * wv;
                }
            }
        }
#pragma unroll
        for (int u = 0; u < 4; ++u) op[oy * 4 + u] = fmaxf(acc[u], 0.0f);
    }
}

// ---- GEMM: C(M,N) = [relu]( A(M,K) @ B(N,K)^T + bias [+ bias2] ) -----------
__global__ __launch_bounds__(256) void gemm_bt(const float* __restrict__ A,
                                               const float* __restrict__ B,
                                               const float* __restrict__ bias,
                                               const float* __restrict__ bias2,
                                               float* __restrict__ C,
                                               int M, int N, int K, int relu) {
    __shared__ float As[16][68];
    __shared__ float Bs[16][68];
    int tid = threadIdx.x;
    int m0 = blockIdx.y * 64, n0 = blockIdx.x * 64;
    int tx = tid & 15, ty = tid >> 4;
    int lr = tid >> 2;
    int lk = (tid & 3) * 4;
    const float* Ap = A + (size_t)(m0 + lr) * K + lk;
    const float* Bp = B + (size_t)(n0 + lr) * K + lk;
    float acc[4][4];
#pragma unroll
    for (int i = 0; i < 4; ++i)
#pragma unroll
        for (int j = 0; j < 4; ++j) acc[i][j] = 0.0f;

    for (int k0 = 0; k0 < K; k0 += 16) {
        float4 av = *(const float4*)(Ap + k0);
        float4 bv = *(const float4*)(Bp + k0);
        __syncthreads();
        As[lk + 0][lr] = av.x;
        As[lk + 1][lr] = av.y;
        As[lk + 2][lr] = av.z;
        As[lk + 3][lr] = av.w;
        Bs[lk + 0][lr] = bv.x;
        Bs[lk + 1][lr] = bv.y;
        Bs[lk + 2][lr] = bv.z;
        Bs[lk + 3][lr] = bv.w;
        __syncthreads();
#pragma unroll
        for (int kk = 0; kk < 16; ++kk) {
            float a[4], b[4];
            *(float4*)a = *(const float4*)&As[kk][ty * 4];
            *(float4*)b = *(const float4*)&Bs[kk][tx * 4];
#pragma unroll
            for (int i = 0; i < 4; ++i)
#pragma unroll
                for (int j = 0; j < 4; ++j) acc[i][j] += a[i] * b[j];
        }
    }
    float bb[4];
#pragma unroll
    for (int j = 0; j < 4; ++j) {
        float v = bias[n0 + tx * 4 + j];
        if (bias2) v += bias2[n0 + tx * 4 + j];
        bb[j] = v;
    }
#pragma unroll
    for (int i = 0; i < 4; ++i) {
        float4 o;
        o.x = acc[i][0] + bb[0];
        o.y = acc[i][1] + bb[1];
        o.z = acc[i][2] + bb[2];
        o.w = acc[i][3] + bb[3];
        if (relu) {
            o.x = fmaxf(o.x, 0.0f);
            o.y = fmaxf(o.y, 0.0f);
            o.z = fmaxf(o.z, 0.0f);
            o.w = fmaxf(o.w, 0.0f);
        }
        *(float4*)&C[(size_t)(m0 + ty * 4 + i) * N + n0 + tx * 4] = o;
    }
}

__device__ inline float fast_tanh(float x) {
    // tanh(x) = 1 - 2/(exp(2x)+1)
    return 1.0f - 2.0f / (__expf(2.0f * x) + 1.0f);
}

// ---- LSTM: 32 blocks (one per env), 1024 threads ---------------------------
// gi (2048,1024) = feats@w_ih^T + b_ih + b_hh (precomputed). w6 = f16-packed
// whh [kg][col][16]: per kg, thread j loads 32 B (2 dwordx4, coalesced — the
// wave covers 2 KB contiguous per instr). h lives in LDS as f16x2 (128 dwords,
// wave-uniform broadcast reads). Inner product via v_dot2_f32_f16 (fp32
// accum): 8 dot2 per 32 MACs vs ~40 VALU instrs in R5 (the measured bound).
// Mask via linearity: (h*m)@W = m*(h@W).
__global__ __launch_bounds__(1024) void lstm_kernel(const float* __restrict__ gi,
                                                    const unsigned short* __restrict__ w6,
                                                    const int* __restrict__ done,
                                                    const float* __restrict__ h0,
                                                    const float* __restrict__ c0,
                                                    float* __restrict__ out) {
    __shared__ alignas(16) unsigned h2u[128];  // h as f16x2, 512 B
    __shared__ float gates[1024];
    int b = blockIdx.x, tid = threadIdx.x;
    float c = 0.0f;
    if (tid < 128) {
        unsigned lo = f2h_bits(h0[b * 256 + tid * 2]);
        unsigned hi = f2h_bits(h0[b * 256 + tid * 2 + 1]);
        h2u[tid] = lo | (hi << 16);
    }
    if (tid < 256) c = c0[b * 256 + tid];
    __syncthreads();
    const uint4* wp = (const uint4*)w6 + tid * 2;  // + kg*2048 (+1 for 2nd half)
    for (int t = 0; t < 64; ++t) {
        int row = t * 32 + b;
        float m = 1.0f - (float)done[row];
        float gv = gi[(size_t)row * 1024 + tid];
        float s0 = 0.f, s1 = 0.f, s2 = 0.f, s3 = 0.f;
#pragma unroll
        for (int kg = 0; kg < 16; ++kg) {
            uint4 wa = wp[(size_t)kg * 2048];
            uint4 wb = wp[(size_t)kg * 2048 + 1];
            uint4 ha = *(const uint4*)&h2u[kg * 8];
            uint4 hb = *(const uint4*)&h2u[kg * 8 + 4];
            s0 = dot2(ha.x, wa.x, s0);
            s1 = dot2(ha.y, wa.y, s1);
            s2 = dot2(ha.z, wa.z, s2);
            s3 = dot2(ha.w, wa.w, s3);
            s0 = dot2(hb.x, wb.x, s0);
            s1 = dot2(hb.y, wb.y, s1);
            s2 = dot2(hb.z, wb.z, s2);
            s3 = dot2(hb.w, wb.w, s3);
        }
        float s = (s0 + s1) + (s2 + s3);
        gates[tid] = gv + m * s;
        __syncthreads();
        if (tid < 256) {
            float g_i = gates[tid];
            float g_f = gates[256 + tid];
            float g_g = gates[512 + tid];
            float g_o = gates[768 + tid];
            float si = 1.0f / (1.0f + __expf(-g_i));
            float sf = 1.0f / (1.0f + __expf(-g_f));
            float so = 1.0f / (1.0f + __expf(-g_o));
            float tg = fast_tanh(g_g);
            c = sf * (c * m) + si * tg;
            float hn = so * fast_tanh(c);
            out[(size_t)row * 256 + tid] = hn;
            float hn2 = __shfl_xor(hn, 1);  // partner's h (lanes 0..255 active)
            if ((tid & 1) == 0) {
                unsigned lo = f2h_bits(hn);
                unsigned hi = f2h_bits(hn2);
                h2u[tid >> 1] = lo | (hi << 16);
            }
        }
        __syncthreads();
    }
}

// ---------------------------------------------------------------------------
extern "C" void kernel_launch(void* const* d_in, const int* in_sizes, int n_in,
                              void* d_out, int out_size, void* d_ws, size_t ws_size,
                              hipStream_t stream) {
    const float* x    = (const float*)d_in[0];
    const int*   done = (const int*)d_in[1];
    const float* w1   = (const float*)d_in[2];
    const float* b1   = (const float*)d_in[3];
    const float* w2   = (const float*)d_in[4];
    const float* b2   = (const float*)d_in[5];
    const float* w3   = (const float*)d_in[6];
    const float* b3   = (const float*)d_in[7];
    const float* fcw  = (const float*)d_in[8];
    const float* fcb  = (const float*)d_in[9];
    const float* wih  = (const float*)d_in[10];
    const float* whh  = (const float*)d_in[11];
    const float* bih  = (const float*)d_in[12];
    const float* bhh  = (const float*)d_in[13];
    const float* h0   = (const float*)d_in[14];
    const float* c0   = (const float*)d_in[15];
    float* out = (float*)d_out;
    float* ws = (float*)d_ws;

    // workspace layout (floats). z3/feats/gi reuse z1's region (z1 dead then).
    float* z1    = ws + 0;          // 14,745,600
    float* z2    = ws + 14745600;   //  4,718,592 (ends 19,464,192)
    float* z3    = ws + 0;          //  2,097,152
    float* feats = ws + 2097152;    //  1,048,576
    float* gi    = ws + 3145728;    //  2,097,152 (ends 5,242,880)
    float* w2t   = ws + 19464192;   //     32,768
    float* w3t   = ws + 19496960;   //     36,864
    unsigned short* w6 = (unsigned short*)(ws + 19533824);  // 512 KB

    transpose_kernel<<<(64 * 512 + 255) / 256, 256, 0, stream>>>(w2, w2t, 64, 512);
    transpose_kernel<<<(64 * 576 + 255) / 256, 256, 0, stream>>>(w3, w3t, 64, 576);
    pack_whh_f16_kernel<<<64, 256, 0, stream>>>(whh, w6);

    conv1_kernel<<<NIMG, 1024, 0, stream>>>(x, w1, b1, z1);
    conv2_kernel<<<NIMG / 2, 768, 0, stream>>>(z1, w2t, b2, z2);
    conv3_kernel<<<NIMG / 4, 512, 0, stream>>>(z2, w3t, b3, z3);

    gemm_bt<<<dim3(512 / 64, NIMG / 64), 256, 0, stream>>>(z3, fcw, fcb, nullptr, feats,
                                                           NIMG, 512, 1024, 1);
    gemm_bt<<<dim3(1024 / 64, NIMG / 64), 256, 0, stream>>>(feats, wih, bih, bhh, gi,
                                                            NIMG, 1024, 512, 0);

    lstm_kernel<<<32, 1024, 0, stream>>>(gi, w6, done, h0, c0, out);
}

// Round 9
// 755.264 us; speedup vs baseline: 2.9535x; 1.2628x over previous
//
#include <hip/hip_runtime.h>
#include <math.h>

// ---------------------------------------------------------------------------
// RecurrentNatureCNN: conv1(8x8,s4) -> conv2(4x4,s2) -> conv3(3x3,s1) -> FC
//                     -> LSTM(T=64,B=32,H=256)
// N = T*B = 2048 images.
// R8: = R7 with compile fix (cvt_pkrtz returns __fp16 vector, not _Float16).
//     conv1+conv2 -> f16 v_dot2_f32_f16 (same trick that took LSTM 506->267):
//     pairs along kx, z1 stored f16 padded (n,32,15,16) — halves conv VALU
//     and z1 HBM traffic. conv3/GEMMs fp32 unchanged. LSTM = R6.
// ---------------------------------------------------------------------------

#define NIMG 2048

typedef _Float16 half2_t __attribute__((ext_vector_type(2)));
typedef __fp16 fp16x2_t __attribute__((ext_vector_type(2)));

__device__ inline unsigned short f2h_bits(float f) {
    union { _Float16 h; unsigned short u; } x;
    x.h = (_Float16)f;
    return x.u;
}

__device__ inline unsigned pack2_rne(float a, float b) {
    return (unsigned)f2h_bits(a) | ((unsigned)f2h_bits(b) << 16);
}

__device__ inline unsigned pack2_fast(float a, float b) {
#if __has_builtin(__builtin_amdgcn_cvt_pkrtz)
    union { fp16x2_t h; unsigned u; } x;
    x.h = __builtin_amdgcn_cvt_pkrtz(a, b);
    return x.u;
#else
    return pack2_rne(a, b);
#endif
}

__device__ inline float dot2(unsigned hu, unsigned wu, float acc) {
    union { unsigned u; half2_t h; } a, b;
    a.u = hu; b.u = wu;
#if __has_builtin(__builtin_amdgcn_fdot2)
    return __builtin_amdgcn_fdot2(a.h, b.h, acc, false);
#else
    return acc + (float)a.h.x * (float)b.h.x + (float)a.h.y * (float)b.h.y;
#endif
}

__device__ inline float fast_tanh(float x) {
    return 1.0f - 2.0f / (__expf(2.0f * x) + 1.0f);
}

// ---- generic small transpose: in (R,C) -> out (C,R) -----------------------
__global__ void transpose_kernel(const float* __restrict__ in, float* __restrict__ out,
                                 int R, int C) {
    int idx = blockIdx.x * 256 + threadIdx.x;
    if (idx < R * C) {
        int r = idx / C, c = idx - r * C;
        out[c * R + r] = in[idx];
    }
}

// ---- pack whh (1024,256) fp32 -> f16: w6[kg][j][16], kg=k/16 ---------------
__global__ void pack_whh_f16_kernel(const float* __restrict__ whh,
                                    unsigned short* __restrict__ w6) {
    int idx = blockIdx.x * 256 + threadIdx.x;  // 0..16383 = kg*1024 + j
    int kg = idx >> 10, j = idx & 1023;
    const float* src = whh + (size_t)j * 256 + kg * 16;
    unsigned short* dst = w6 + (size_t)idx * 16;
#pragma unroll
    for (int i = 0; i < 16; ++i) dst[i] = f2h_bits(src[i]);
}

// ---- pack w1 (32,4,8,8) fp32 -> f16x2 pairs along kx: w1p[oc][ic][ky][kxp] -
__global__ void pack_w1_kernel(const float* __restrict__ w1, unsigned* __restrict__ w1p) {
    int idx = blockIdx.x * 256 + threadIdx.x;  // 0..4095
    if (idx >= 4096) return;
    int oc = idx >> 7, rem = idx & 127;
    int ic = rem >> 5, ky = (rem >> 2) & 7, kxp = rem & 3;
    const float* src = w1 + (((size_t)oc * 4 + ic) * 8 + ky) * 8 + kxp * 2;
    w1p[idx] = pack2_rne(src[0], src[1]);
}

// ---- pack w2 (64,32,4,4) fp32 -> f16x2 pairs: w2p[(ic*4+ky)*2+kxp][oc] -----
__global__ void pack_w2_kernel(const float* __restrict__ w2, unsigned* __restrict__ w2p) {
    int idx = blockIdx.x * 256 + threadIdx.x;  // 0..16383
    if (idx >= 16384) return;
    int p = idx >> 6, oc = idx & 63;
    int ic = p >> 3, ky = (p >> 1) & 3, kxp = p & 1;
    const float* src = w2 + (size_t)oc * 512 + ic * 16 + ky * 4 + kxp * 2;
    w2p[idx] = pack2_rne(src[0], src[1]);
}

// ---- conv1: x (n,4,64,64)/255 -> relu -> z1 f16 (n,32,15,16 padded) --------
// block = 1 image, 1024 threads (16 waves). wave w: oc-group g=w&3 (8 oc),
// position (w>>2)*64+lane. Image staged as f16 in LDS (32 KB). Inner product
// via dot2: pairs along kx (window start ox*4 even -> dword-aligned pairs).
__global__ __launch_bounds__(1024) void conv1_kernel(const float* __restrict__ x,
                                                     const unsigned* __restrict__ w1p,
                                                     const float* __restrict__ b,
                                                     unsigned short* __restrict__ z1) {
    __shared__ unsigned short xs[4 * 64 * 64];  // f16, 32768 B
    int n = blockIdx.x;
    int tid = threadIdx.x;
    const float* xp = x + (size_t)n * 16384;
    const float inv = 1.0f / 255.0f;
    for (int i = tid * 4; i < 16384; i += 4096) {
        float4 v = *(const float4*)(xp + i);
        uint2 q;
        q.x = pack2_fast(v.x * inv, v.y * inv);
        q.y = pack2_fast(v.z * inv, v.w * inv);
        *(uint2*)&xs[i] = q;
    }
    __syncthreads();
    int lane = tid & 63, wave = tid >> 6;
    int gg = __builtin_amdgcn_readfirstlane(wave & 3);
    int pos = (wave >> 2) * 64 + lane;  // 0..255
    if (pos < 225) {
        int oy = pos / 15, ox = pos - oy * 15;
        float acc[8];
        const float* bp = b + gg * 8;
#pragma unroll
        for (int u = 0; u < 8; ++u) acc[u] = bp[u];
        for (int ic = 0; ic < 4; ++ic) {
#pragma unroll
            for (int ky = 0; ky < 8; ++ky) {
                const unsigned short* row = &xs[(ic * 64 + oy * 4 + ky) * 64 + ox * 4];
                uint2 qa = *(const uint2*)row;        // cols +0..3 (2 pairs)
                uint2 qb = *(const uint2*)(row + 4);  // cols +4..7 (2 pairs)
                const unsigned* wp = w1p + ((((gg * 8) * 4 + ic) * 8 + ky) * 4);
#pragma unroll
                for (int u = 0; u < 8; ++u) {
                    const unsigned* wu = wp + u * 128;  // (oc stride 4*8*4)
                    acc[u] = dot2(qa.x, wu[0], acc[u]);
                    acc[u] = dot2(qa.y, wu[1], acc[u]);
                    acc[u] = dot2(qb.x, wu[2], acc[u]);
                    acc[u] = dot2(qb.y, wu[3], acc[u]);
                }
            }
        }
        unsigned short* op = z1 + (size_t)n * 7680 + (gg * 8) * 240 + oy * 16 + ox;
#pragma unroll
        for (int u = 0; u < 8; ++u) op[u * 240] = f2h_bits(fmaxf(acc[u], 0.0f));
    }
}

// ---- conv2: z1 f16 (n,32,15,16) -> relu -> z2 fp32 (n,64,6,6) --------------
// block = 2 images, 768 threads. Staging = straight dword copy (padded rows).
// wave = (img, oy), lane = oc. dot2 pairs along kx (window start oy*2 even).
__global__ __launch_bounds__(768) void conv2_kernel(const unsigned short* __restrict__ z1,
                                                    const unsigned* __restrict__ w2p,
                                                    const float* __restrict__ bias,
                                                    float* __restrict__ out) {
    __shared__ unsigned short xs[2][32 * 15 * 16];  // f16, 30720 B
    int tid = threadIdx.x;
    int n0 = blockIdx.x * 2;
#pragma unroll
    for (int img = 0; img < 2; ++img) {
        const unsigned* src = (const unsigned*)(z1 + (size_t)(n0 + img) * 7680);
        unsigned* dst = (unsigned*)xs[img];
        for (int i = tid; i < 3840; i += 768) dst[i] = src[i];
    }
    __syncthreads();
    int lane = tid & 63, wave = tid >> 6;  // wave 0..11
    int img = wave / 6;
    int oy = wave - img * 6;
    int n = n0 + img;
    float bv = bias[lane];
    float* op = out + (size_t)n * 2304 + lane * 36;
    float acc[6];
#pragma unroll
    for (int u = 0; u < 6; ++u) acc[u] = bv;
    for (int ic = 0; ic < 32; ++ic) {
#pragma unroll
        for (int ky = 0; ky < 4; ++ky) {
            const unsigned short* row = &xs[img][(ic * 15 + oy * 2 + ky) * 16];
            uint4 pa = *(const uint4*)row;        // pairs 0..3  (cols 0..7)
            uint4 pb = *(const uint4*)(row + 8);  // pairs 4..7  (cols 8..15)
            unsigned p[8] = {pa.x, pa.y, pa.z, pa.w, pb.x, pb.y, pb.z, pb.w};
            const unsigned* wpp = w2p + ((ic * 4 + ky) * 2) * 64 + lane;
            unsigned wa = wpp[0];   // kx 0,1
            unsigned wb = wpp[64];  // kx 2,3
#pragma unroll
            for (int u = 0; u < 6; ++u) {
                acc[u] = dot2(p[u], wa, acc[u]);
                acc[u] = dot2(p[u + 1], wb, acc[u]);
            }
        }
    }
#pragma unroll
    for (int u = 0; u < 6; ++u) op[oy * 6 + u] = fmaxf(acc[u], 0.0f);
}

// ---- conv3: z2 (n,64,6,6) -> relu -> (n,64,4,4)  (fp32, unchanged) ---------
__global__ __launch_bounds__(512) void conv3_kernel(const float* __restrict__ x,
                                                    const float* __restrict__ wt,
                                                    const float* __restrict__ bias,
                                                    float* __restrict__ out) {
    __shared__ float xs[4][64 * 6 * 8];  // 49152 B
    int tid = threadIdx.x;
    int n0 = blockIdx.x * 4;
    for (int img = 0; img < 4; ++img) {
        const float* src = x + (size_t)(n0 + img) * 2304;
        for (int s = tid; s < 2304; s += 512) {
            int ic = s / 36;
            int rem = s - ic * 36;
            int r = rem / 6;
            int c = rem - r * 6;
            xs[img][(ic * 6 + r) * 8 + c] = src[s];
        }
    }
    __syncthreads();
    int lane = tid & 63, wave = tid >> 6;  // 0..7
    int img = wave >> 1;
    int half = wave & 1;
    int n = n0 + img;
    float bv = bias[lane];
    float* op = out + (size_t)n * 1024 + lane * 16;
    for (int q = 0; q < 2; ++q) {
        int oy = half * 2 + q;
        float acc[4];
#pragma unroll
        for (int u = 0; u < 4; ++u) acc[u] = bv;
        for (int ic = 0; ic < 64; ++ic) {
#pragma unroll
            for (int ky = 0; ky < 3; ++ky) {
                const float* xrow = &xs[img][(ic * 6 + oy + ky) * 8];
                float xr[8];
                *(float4*)&xr[0] = *(const float4*)&xrow[0];
                *(float4*)&xr[4] = *(const float4*)&xrow[4];
                const float* wp = wt + ((ic * 3 + ky) * 3) * 64 + lane;
#pragma unroll
                for (int kx = 0; kx < 3; ++kx) {
                    float wv = wp[kx * 64];
#pragma unroll
                    for (int u = 0; u < 4; ++u) acc[u] += xr[u + kx] * wv;
                }
            }
        }
#pragma unroll
        for (int u = 0; u < 4; ++u) op[oy * 4 + u] = fmaxf(acc[u], 0.0f);
    }
}

// ---- GEMM: C(M,N) = [relu]( A(M,K) @ B(N,K)^T + bias [+ bias2] ) -----------
__global__ __launch_bounds__(256) void gemm_bt(const float* __restrict__ A,
                                               const float* __restrict__ B,
                                               const float* __restrict__ bias,
                                               const float* __restrict__ bias2,
                                               float* __restrict__ C,
                                               int M, int N, int K, int relu) {
    __shared__ float As[16][68];
    __shared__ float Bs[16][68];
    int tid = threadIdx.x;
    int m0 = blockIdx.y * 64, n0 = blockIdx.x * 64;
    int tx = tid & 15, ty = tid >> 4;
    int lr = tid >> 2;
    int lk = (tid & 3) * 4;
    const float* Ap = A + (size_t)(m0 + lr) * K + lk;
    const float* Bp = B + (size_t)(n0 + lr) * K + lk;
    float acc[4][4];
#pragma unroll
    for (int i = 0; i < 4; ++i)
#pragma unroll
        for (int j = 0; j < 4; ++j) acc[i][j] = 0.0f;

    for (int k0 = 0; k0 < K; k0 += 16) {
        float4 av = *(const float4*)(Ap + k0);
        float4 bv = *(const float4*)(Bp + k0);
        __syncthreads();
        As[lk + 0][lr] = av.x;
        As[lk + 1][lr] = av.y;
        As[lk + 2][lr] = av.z;
        As[lk + 3][lr] = av.w;
        Bs[lk + 0][lr] = bv.x;
        Bs[lk + 1][lr] = bv.y;
        Bs[lk + 2][lr] = bv.z;
        Bs[lk + 3][lr] = bv.w;
        __syncthreads();
#pragma unroll
        for (int kk = 0; kk < 16; ++kk) {
            float a[4], b[4];
            *(float4*)a = *(const float4*)&As[kk][ty * 4];
            *(float4*)b = *(const float4*)&Bs[kk][tx * 4];
#pragma unroll
            for (int i = 0; i < 4; ++i)
#pragma unroll
                for (int j = 0; j < 4; ++j) acc[i][j] += a[i] * b[j];
        }
    }
    float bb[4];
#pragma unroll
    for (int j = 0; j < 4; ++j) {
        float v = bias[n0 + tx * 4 + j];
        if (bias2) v += bias2[n0 + tx * 4 + j];
        bb[j] = v;
    }
#pragma unroll
    for (int i = 0; i < 4; ++i) {
        float4 o;
        o.x = acc[i][0] + bb[0];
        o.y = acc[i][1] + bb[1];
        o.z = acc[i][2] + bb[2];
        o.w = acc[i][3] + bb[3];
        if (relu) {
            o.x = fmaxf(o.x, 0.0f);
            o.y = fmaxf(o.y, 0.0f);
            o.z = fmaxf(o.z, 0.0f);
            o.w = fmaxf(o.w, 0.0f);
        }
        *(float4*)&C[(size_t)(m0 + ty * 4 + i) * N + n0 + tx * 4] = o;
    }
}

// ---- LSTM: 32 blocks (one per env), 1024 threads (R6, unchanged) -----------
__global__ __launch_bounds__(1024) void lstm_kernel(const float* __restrict__ gi,
                                                    const unsigned short* __restrict__ w6,
                                                    const int* __restrict__ done,
                                                    const float* __restrict__ h0,
                                                    const float* __restrict__ c0,
                                                    float* __restrict__ out) {
    __shared__ alignas(16) unsigned h2u[128];  // h as f16x2, 512 B
    __shared__ float gates[1024];
    int b = blockIdx.x, tid = threadIdx.x;
    float c = 0.0f;
    if (tid < 128) {
        unsigned lo = f2h_bits(h0[b * 256 + tid * 2]);
        unsigned hi = f2h_bits(h0[b * 256 + tid * 2 + 1]);
        h2u[tid] = lo | (hi << 16);
    }
    if (tid < 256) c = c0[b * 256 + tid];
    __syncthreads();
    const uint4* wp = (const uint4*)w6 + tid * 2;  // + kg*2048 (+1 for 2nd half)
    for (int t = 0; t < 64; ++t) {
        int row = t * 32 + b;
        float m = 1.0f - (float)done[row];
        float gv = gi[(size_t)row * 1024 + tid];
        float s0 = 0.f, s1 = 0.f, s2 = 0.f, s3 = 0.f;
#pragma unroll
        for (int kg = 0; kg < 16; ++kg) {
            uint4 wa = wp[(size_t)kg * 2048];
            uint4 wb = wp[(size_t)kg * 2048 + 1];
            uint4 ha = *(const uint4*)&h2u[kg * 8];
            uint4 hb = *(const uint4*)&h2u[kg * 8 + 4];
            s0 = dot2(ha.x, wa.x, s0);
            s1 = dot2(ha.y, wa.y, s1);
            s2 = dot2(ha.z, wa.z, s2);
            s3 = dot2(ha.w, wa.w, s3);
            s0 = dot2(hb.x, wb.x, s0);
            s1 = dot2(hb.y, wb.y, s1);
            s2 = dot2(hb.z, wb.z, s2);
            s3 = dot2(hb.w, wb.w, s3);
        }
        float s = (s0 + s1) + (s2 + s3);
        gates[tid] = gv + m * s;
        __syncthreads();
        if (tid < 256) {
            float g_i = gates[tid];
            float g_f = gates[256 + tid];
            float g_g = gates[512 + tid];
            float g_o = gates[768 + tid];
            float si = 1.0f / (1.0f + __expf(-g_i));
            float sf = 1.0f / (1.0f + __expf(-g_f));
            float so = 1.0f / (1.0f + __expf(-g_o));
            float tg = fast_tanh(g_g);
            c = sf * (c * m) + si * tg;
            float hn = so * fast_tanh(c);
            out[(size_t)row * 256 + tid] = hn;
            float hn2 = __shfl_xor(hn, 1);
            if ((tid & 1) == 0) {
                unsigned lo = f2h_bits(hn);
                unsigned hi = f2h_bits(hn2);
                h2u[tid >> 1] = lo | (hi << 16);
            }
        }
        __syncthreads();
    }
}

// ---------------------------------------------------------------------------
extern "C" void kernel_launch(void* const* d_in, const int* in_sizes, int n_in,
                              void* d_out, int out_size, void* d_ws, size_t ws_size,
                              hipStream_t stream) {
    const float* x    = (const float*)d_in[0];
    const int*   done = (const int*)d_in[1];
    const float* w1   = (const float*)d_in[2];
    const float* b1   = (const float*)d_in[3];
    const float* w2   = (const float*)d_in[4];
    const float* b2   = (const float*)d_in[5];
    const float* w3   = (const float*)d_in[6];
    const float* b3   = (const float*)d_in[7];
    const float* fcw  = (const float*)d_in[8];
    const float* fcb  = (const float*)d_in[9];
    const float* wih  = (const float*)d_in[10];
    const float* whh  = (const float*)d_in[11];
    const float* bih  = (const float*)d_in[12];
    const float* bhh  = (const float*)d_in[13];
    const float* h0   = (const float*)d_in[14];
    const float* c0   = (const float*)d_in[15];
    float* out = (float*)d_out;
    float* ws = (float*)d_ws;

    // workspace layout (float offsets):
    // z1u (f16): [0, 7,864,320)   -- (2048, 32, 15, 16) shorts
    // z2:        [8,000,000, 12,718,592)
    // z3:        [0, 2,097,152)           (z1u dead after conv2)
    // feats:     [2,097,152, 3,145,728)
    // gi:        [3,145,728, 5,242,880)
    // w3t:       [13,000,000, +36,864)
    // w1p:       [13,100,000, +4,096)   (uint)
    // w2p:       [13,200,000, +16,384)  (uint)
    // w6:        [13,300,000, +131,072) (f16)   ends 13.43M floats = 53.7 MB
    unsigned short* z1u = (unsigned short*)(ws + 0);
    float* z2    = ws + 8000000;
    float* z3    = ws + 0;
    float* feats = ws + 2097152;
    float* gi    = ws + 3145728;
    float* w3t   = ws + 13000000;
    unsigned* w1p = (unsigned*)(ws + 13100000);
    unsigned* w2p = (unsigned*)(ws + 13200000);
    unsigned short* w6 = (unsigned short*)(ws + 13300000);

    transpose_kernel<<<(64 * 576 + 255) / 256, 256, 0, stream>>>(w3, w3t, 64, 576);
    pack_whh_f16_kernel<<<64, 256, 0, stream>>>(whh, w6);
    pack_w1_kernel<<<16, 256, 0, stream>>>(w1, w1p);
    pack_w2_kernel<<<64, 256, 0, stream>>>(w2, w2p);

    conv1_kernel<<<NIMG, 1024, 0, stream>>>(x, w1p, b1, z1u);
    conv2_kernel<<<NIMG / 2, 768, 0, stream>>>(z1u, w2p, b2, z2);
    conv3_kernel<<<NIMG / 4, 512, 0, stream>>>(z2, w3t, b3, z3);

    gemm_bt<<<dim3(512 / 64, NIMG / 64), 256, 0, stream>>>(z3, fcw, fcb, nullptr, feats,
                                                           NIMG, 512, 1024, 1);
    gemm_bt<<<dim3(1024 / 64, NIMG / 64), 256, 0, stream>>>(feats, wih, bih, bhh, gi,
                                                            NIMG, 1024, 512, 0);

    lstm_kernel<<<32, 1024, 0, stream>>>(gi, w6, done, h0, c0, out);
}